// Round 12
// baseline (310.190 us; speedup 1.0000x reference)
//
#include <hip/hip_runtime.h>
#include <hip/hip_bf16.h>

// RPN proposal: top-2000 -> decode/clip -> greedy NMS -> top-1000 proposals.
// Pipeline: init -> hist(2048 bins) -> threshold -> collect -> bitonic sort ->
//           decode -> IoU bitmask (ROW-MAJOR, tile-contiguous) -> blocked
//           serial NMS (SALU chain + predicated vector rem) -> scatter out.
//
// NMS evolution (measured): R7 315us (global loads on chain) -> R8 87.6us
// (un-pipelined LDS reads on chain) -> R9 61.5us (VGPR pressure broke the
// reg-pipeline; 64-bit VALU chain issue-bound). R10: row-major tiles make
// staging linear and LDS row reads immediate-offset; serial chain moved to
// SALU via v_readlane; rem update predicated via scalar masks + cndmask.

typedef unsigned int uint;
typedef unsigned long long ull;

#define PRE_NMS   2000
#define POST_NMS  1000
#define SORT_N    4096
#define NBINS     2048
#define NMS_TH    0.7f
#define MIN_SIZE  1.0f
#define BBOX_CLIP 4.135166556742356f   // float(ln(1000/16))

// ---- ws layout (bytes) ----
#define HIST_OFF    0        // 2048 * 4 = 8192
#define META_OFF    8192     // 64 uints (meta[0]=threshold bin, meta[1]=cand count)
#define VALID_OFF   8448     // 32 * 8 = 256
#define CAND_OFF    8704     // 4096 * 8 = 32768
#define TOPIDX_OFF  41472    // 2000 * 4 = 8000
#define BOXES_OFF   49472    // 2000 * 16 = 32000 (16B aligned)
#define MASK_OFF    81472    // 2048 rows * 32 cols * 8 = 524288
#define REM_OFF     605760   // 32 * 8 = 256
#define ZERO_WORDS  2176     // (hist + meta + validWords) / 4 = 8704 B

__device__ __forceinline__ uint map_f32(float f) {
    uint u = __float_as_uint(f);
    return u ^ ((u & 0x80000000u) ? 0xFFFFFFFFu : 0x80000000u);
}

// ---------------- 0. zero ws header + output --------------------------------
__global__ __launch_bounds__(256) void init_kernel(uint* __restrict__ wsHead,
                                                   float4* __restrict__ out) {
    int t = blockIdx.x * 256 + threadIdx.x;
    if (t < ZERO_WORDS) wsHead[t] = 0u;
    if (t < POST_NMS) out[t] = make_float4(0.f, 0.f, 0.f, 0.f);
}

// ---------------- 1. histogram of top 11 bits of mapped score ----------------
__global__ __launch_bounds__(256) void hist_kernel(const float* __restrict__ obj,
                                                   int n, uint* __restrict__ hist) {
    __shared__ uint h[NBINS];
    for (int b = threadIdx.x; b < NBINS; b += 256) h[b] = 0;
    __syncthreads();
    int n4 = n >> 2;
    const float4* obj4 = reinterpret_cast<const float4*>(obj);
    int stride = gridDim.x * blockDim.x;
    for (int i = blockIdx.x * blockDim.x + threadIdx.x; i < n4; i += stride) {
        float4 v = obj4[i];
        atomicAdd(&h[map_f32(v.x) >> 21], 1u);
        atomicAdd(&h[map_f32(v.y) >> 21], 1u);
        atomicAdd(&h[map_f32(v.z) >> 21], 1u);
        atomicAdd(&h[map_f32(v.w) >> 21], 1u);
    }
    int base = n4 << 2;
    for (int i = base + blockIdx.x * blockDim.x + threadIdx.x; i < n; i += stride)
        atomicAdd(&h[map_f32(obj[i]) >> 21], 1u);
    __syncthreads();
    for (int b = threadIdx.x; b < NBINS; b += 256)
        if (h[b]) atomicAdd(&hist[b], h[b]);
}

// ---------------- 2. find threshold bin (cum-from-top crosses PRE_NMS) -------
__global__ __launch_bounds__(256) void thresh_kernel(const uint* __restrict__ hist,
                                                     uint* __restrict__ meta) {
    __shared__ uint s_sum[256];
    __shared__ uint s_suf[256];
    int t = threadIdx.x;
    uint local[8];
    uint sum = 0;
#pragma unroll 8
    for (int b = 0; b < 8; b++) { local[b] = hist[t * 8 + b]; sum += local[b]; }
    s_sum[t] = sum;
    __syncthreads();
    if (t == 0) {
        uint acc = 0;
        for (int c = 255; c >= 0; c--) { s_suf[c] = acc; acc += s_sum[c]; }
    }
    __syncthreads();
    uint c = s_suf[t];  // count strictly above this chunk
#pragma unroll 8
    for (int b = 7; b >= 0; b--) {
        uint nc = c + local[b];
        if (c < (uint)PRE_NMS && nc >= (uint)PRE_NMS) meta[0] = (uint)(t * 8 + b);
        c = nc;
    }
}

// ---------------- 3. collect candidates >= threshold bin ---------------------
__global__ __launch_bounds__(256) void collect_kernel(const float* __restrict__ obj,
                                                      int n, uint* __restrict__ meta,
                                                      ull* __restrict__ cand) {
    uint T = meta[0];
    int n4 = n >> 2;
    const float4* obj4 = reinterpret_cast<const float4*>(obj);
    int stride = gridDim.x * blockDim.x;
    for (int i = blockIdx.x * blockDim.x + threadIdx.x; i < n4; i += stride) {
        float4 v = obj4[i];
        uint u0 = map_f32(v.x), u1 = map_f32(v.y), u2 = map_f32(v.z), u3 = map_f32(v.w);
        if ((u0 >> 21) >= T) {
            uint pos = atomicAdd(&meta[1], 1u);
            if (pos < (uint)SORT_N) cand[pos] = ((ull)u0 << 32) | (ull)(~(uint)(i * 4 + 0));
        }
        if ((u1 >> 21) >= T) {
            uint pos = atomicAdd(&meta[1], 1u);
            if (pos < (uint)SORT_N) cand[pos] = ((ull)u1 << 32) | (ull)(~(uint)(i * 4 + 1));
        }
        if ((u2 >> 21) >= T) {
            uint pos = atomicAdd(&meta[1], 1u);
            if (pos < (uint)SORT_N) cand[pos] = ((ull)u2 << 32) | (ull)(~(uint)(i * 4 + 2));
        }
        if ((u3 >> 21) >= T) {
            uint pos = atomicAdd(&meta[1], 1u);
            if (pos < (uint)SORT_N) cand[pos] = ((ull)u3 << 32) | (ull)(~(uint)(i * 4 + 3));
        }
    }
    int base = n4 << 2;
    for (int i = base + blockIdx.x * blockDim.x + threadIdx.x; i < n; i += stride) {
        uint u = map_f32(obj[i]);
        if ((u >> 21) >= T) {
            uint pos = atomicAdd(&meta[1], 1u);
            if (pos < (uint)SORT_N) cand[pos] = ((ull)u << 32) | (ull)(~(uint)i);
        }
    }
}

// ---------------- 4. bitonic sort (descending), emit top-2000 indices --------
__global__ __launch_bounds__(1024) void sort_kernel(const ull* __restrict__ cand,
                                                    const uint* __restrict__ meta,
                                                    int* __restrict__ topIdx) {
    __shared__ ull keys[SORT_N];
    uint n = meta[1]; if (n > (uint)SORT_N) n = SORT_N;
    for (int t = threadIdx.x; t < SORT_N; t += 1024)
        keys[t] = (t < (int)n) ? cand[t] : 0ULL;
    __syncthreads();
    for (int k = 2; k <= SORT_N; k <<= 1) {
        for (int j = k >> 1; j > 0; j >>= 1) {
            for (int t = threadIdx.x; t < SORT_N; t += 1024) {
                int ixj = t ^ j;
                if (ixj > t) {
                    ull A = keys[t], B = keys[ixj];
                    bool desc = ((t & k) == 0);
                    if (desc ? (A < B) : (A > B)) { keys[t] = B; keys[ixj] = A; }
                }
            }
            __syncthreads();
        }
    }
    for (int t = threadIdx.x; t < PRE_NMS; t += 1024)
        topIdx[t] = (int)(~(uint)keys[t]);   // low32 stored as ~idx
}

// ---------------- 5. gather + decode + clip + valid --------------------------
__global__ __launch_bounds__(256) void decode_kernel(const float* __restrict__ anchor,
                                                     const float* __restrict__ delta,
                                                     const int* __restrict__ topIdx,
                                                     const int* __restrict__ imh,
                                                     const int* __restrict__ imw,
                                                     float4* __restrict__ boxes,
                                                     ull* __restrict__ validWords) {
    int i = blockIdx.x * blockDim.x + threadIdx.x;
    if (i >= PRE_NMS) return;
    int idx = topIdx[i];
    const float4 a = reinterpret_cast<const float4*>(anchor)[idx];
    const float4 d = reinterpret_cast<const float4*>(delta)[idx];
    float W = (float)imw[0], H = (float)imh[0];
    float w  = a.z - a.x;
    float h  = a.w - a.y;
    float cx = a.x + 0.5f * w;
    float cy = a.y + 0.5f * h;
    float dw = fminf(d.z, BBOX_CLIP);
    float dh = fminf(d.w, BBOX_CLIP);
    float pcx = d.x * w + cx;
    float pcy = d.y * h + cy;
    float pw  = expf(dw) * w;
    float ph  = expf(dh) * h;
    float x1 = fminf(fmaxf(pcx - 0.5f * pw, 0.0f), W);
    float y1 = fminf(fmaxf(pcy - 0.5f * ph, 0.0f), H);
    float x2 = fminf(fmaxf(pcx + 0.5f * pw, 0.0f), W);
    float y2 = fminf(fmaxf(pcy + 0.5f * ph, 0.0f), H);
    boxes[i] = make_float4(x1, y1, x2, y2);
    bool valid = (x2 - x1 >= MIN_SIZE) && (y2 - y1 >= MIN_SIZE);
    if (valid) atomicOr(&validWords[i >> 6], 1ULL << (i & 63));
}

// ---------------- 6. suppression bitmatrix, ROW-MAJOR ------------------------
// gmask[r*32 + c] = word c of row r (bits for rows 64c..64c+63, j>r only).
// Tile w (rows 64w..64w+63) is a contiguous 16 KB block.
__global__ __launch_bounds__(256) void mask_kernel(const float4* __restrict__ boxes,
                                                   ull* __restrict__ gmask) {
    __shared__ float4 b[PRE_NMS];
    for (int t = threadIdx.x; t < PRE_NMS; t += 256) b[t] = boxes[t];
    __syncthreads();
    int tid = blockIdx.x * 256 + threadIdx.x;   // 0 .. 65535
    int r = tid >> 5;           // row 0..2047
    int c = tid & 31;           // word 0..31
    ull m = 0;
    if (r < PRE_NMS) {
        float4 bi = b[r];
        float areai = (bi.z - bi.x) * (bi.w - bi.y);
        int j0 = c * 64;
#pragma unroll
        for (int jj = 0; jj < 64; jj++) {
            int j = j0 + jj;
            if (j < PRE_NMS && j > r) {
                float4 bj = b[j];
                float xx1 = fmaxf(bi.x, bj.x), yy1 = fmaxf(bi.y, bj.y);
                float xx2 = fminf(bi.z, bj.z), yy2 = fminf(bi.w, bj.w);
                float inter = fmaxf(xx2 - xx1, 0.0f) * fmaxf(yy2 - yy1, 0.0f);
                float areaj = (bj.z - bj.x) * (bj.w - bj.y);
                float iou = inter / (areai + areaj - inter + 1e-9f);
                if (iou > NMS_TH) m |= (1ULL << jj);
            }
        }
    }
    gmask[tid] = m;   // tid == r*32 + c, coalesced
}

// ---------------- 7. blocked serial greedy NMS (1 wave) ----------------------
// Tile w = rows [64w,64w+64), contiguous 16 KB, staged linearly into LDS.
// One ds_read_b64 per ROW PAIR (lanes 0-31 row i, lanes 32-63 row i+1).
// Serial keep-chain in SALU: d words via v_readlane(o, w / w+32);
// rem update predicated via scalar act masks + v_cndmask (no branches).
__device__ __forceinline__ void nms_stage_tile(const char* gm, void* dst,
                                               int w, int lane) {
    const char* src = gm + (size_t)w * 16384 + (size_t)(lane * 16);
#pragma unroll
    for (int k = 0; k < 16; ++k) {
        __builtin_amdgcn_global_load_lds(
            (const __attribute__((address_space(1))) uint*)(src + k * 1024),
            (__attribute__((address_space(3))) uint*)((char*)dst + k * 1024),
            16, 0, 0);
    }
}

__global__ __launch_bounds__(64) void nms_kernel(const ull* __restrict__ gmask,
                                                 const ull* __restrict__ validWords,
                                                 ull* __restrict__ remOut) {
    __shared__ __align__(16) ull buf[2][2048];   // 2 x (64 rows x 32 cols) = 32 KB
    const int lane = threadIdx.x;
    const int lw = lane & 31;
    const bool hiHalf = lane >= 32;
    ull rem = hiHalf ? 0ULL : ~validWords[lw];   // removed = !valid (lanes<32)
    const char* gm = (const char*)gmask;

    nms_stage_tile(gm, &buf[0][0], 0, lane);     // prologue: tile 0

    for (int w = 0; w < 32; ++w) {
        const int b = w & 1;
        if (w + 1 < 32) {
            nms_stage_tile(gm, &buf[b ^ 1][0], w + 1, lane);
            asm volatile("s_waitcnt vmcnt(16)" ::: "memory");  // tile w landed
        } else {
            asm volatile("s_waitcnt vmcnt(0)" ::: "memory");
        }
        __builtin_amdgcn_sched_barrier(0);

        // scalar running word for this tile: combine both lane-half accumulators
        const int w32 = w + 32;
        uint r0 = (uint)__builtin_amdgcn_readlane((int)(uint)rem, w);
        uint r1 = (uint)__builtin_amdgcn_readlane((int)(uint)(rem >> 32), w);
        uint r2 = (uint)__builtin_amdgcn_readlane((int)(uint)rem, w32);
        uint r3 = (uint)__builtin_amdgcn_readlane((int)(uint)(rem >> 32), w32);
        ull rw = (((ull)(r1 | r3)) << 32) | (ull)(r0 | r2);

        // per-lane LDS base: row parity via lane half, col via lane&31
        const char* base = (const char*)&buf[b][0] + (hiHalf ? 256 : 0) + lw * 8;

#pragma unroll
        for (int ch = 0; ch < 4; ++ch) {
            ull o[8];
#pragma unroll
            for (int p = 0; p < 8; ++p)          // ds_read_b64, imm offsets
                o[p] = *(const ull*)(base + (ch * 16 + 2 * p) * 256);
#pragma unroll
            for (int p = 0; p < 8; ++p) {
                const int i0 = ch * 16 + 2 * p, i1 = i0 + 1;
                uint dlo0 = (uint)__builtin_amdgcn_readlane((int)(uint)o[p], w);
                uint dhi0 = (uint)__builtin_amdgcn_readlane((int)(uint)(o[p] >> 32), w);
                uint dlo1 = (uint)__builtin_amdgcn_readlane((int)(uint)o[p], w32);
                uint dhi1 = (uint)__builtin_amdgcn_readlane((int)(uint)(o[p] >> 32), w32);
                ull d0 = (((ull)dhi0) << 32) | dlo0;
                ull d1 = (((ull)dhi1) << 32) | dlo1;
                bool a0 = ((rw >> i0) & 1ULL) == 0ULL;
                rw |= a0 ? d0 : 0ULL;
                bool a1 = ((rw >> i1) & 1ULL) == 0ULL;
                rw |= a1 ? d1 : 0ULL;
                uint m0 = a0 ? ~0u : 0u;         // scalar masks
                uint m1 = a1 ? ~0u : 0u;
                uint ms = hiHalf ? m1 : m0;      // one v_cndmask
                rem |= o[p] & ((((ull)ms) << 32) | (ull)ms);
            }
        }
    }
    // combine lane-half accumulators: lane l<32 ORs lane l+32's rem
    ull other = __shfl(rem, lane + 32, 64);
    rem |= other;
    if (lane < 32) remOut[lw] = rem;
}

// ---------------- 8. scatter kept boxes in positional (score) order ----------
__global__ __launch_bounds__(256) void output_kernel(const float4* __restrict__ boxes,
                                                     const ull* __restrict__ rem,
                                                     float4* __restrict__ out) {
    __shared__ uint pre[33];
    __shared__ ull kept_s[32];
    int t = threadIdx.x;
    if (t < 32) kept_s[t] = ~rem[t];
    __syncthreads();
    if (t == 0) {
        uint acc = 0;
        for (int w = 0; w < 32; w++) { pre[w] = acc; acc += (uint)__popcll(kept_s[w]); }
        pre[32] = acc;
    }
    __syncthreads();
    for (int i = t; i < PRE_NMS; i += 256) {
        ull kw = kept_s[i >> 6];
        if ((kw >> (i & 63)) & 1ULL) {
            uint rank = pre[i >> 6] +
                        (uint)__popcll(kw & ((1ULL << (i & 63)) - 1ULL));
            if (rank < (uint)POST_NMS) out[rank] = boxes[i];
        }
    }
}

extern "C" void kernel_launch(void* const* d_in, const int* in_sizes, int n_in,
                              void* d_out, int out_size, void* d_ws, size_t ws_size,
                              hipStream_t stream) {
    const float* anchor = (const float*)d_in[0];
    const float* obj    = (const float*)d_in[1];
    const float* delta  = (const float*)d_in[2];
    const int*   imh    = (const int*)d_in[3];
    const int*   imw    = (const int*)d_in[4];
    int n = in_sizes[1];

    char* ws = (char*)d_ws;
    uint* hist       = (uint*)(ws + HIST_OFF);
    uint* meta       = (uint*)(ws + META_OFF);
    ull*  validWords = (ull*)(ws + VALID_OFF);
    ull*  cand       = (ull*)(ws + CAND_OFF);
    int*  topIdx     = (int*)(ws + TOPIDX_OFF);
    float4* boxes    = (float4*)(ws + BOXES_OFF);
    ull*  gmask      = (ull*)(ws + MASK_OFF);
    ull*  rem        = (ull*)(ws + REM_OFF);

    init_kernel<<<(ZERO_WORDS + 255) / 256, 256, 0, stream>>>(
        (uint*)ws, (float4*)d_out);
    hist_kernel<<<512, 256, 0, stream>>>(obj, n, hist);
    thresh_kernel<<<1, 256, 0, stream>>>(hist, meta);
    collect_kernel<<<512, 256, 0, stream>>>(obj, n, meta, cand);
    sort_kernel<<<1, 1024, 0, stream>>>(cand, meta, topIdx);
    decode_kernel<<<(PRE_NMS + 255) / 256, 256, 0, stream>>>(
        anchor, delta, topIdx, imh, imw, boxes, validWords);
    mask_kernel<<<(32 * 2048) / 256, 256, 0, stream>>>(boxes, gmask);
    nms_kernel<<<1, 64, 0, stream>>>(gmask, validWords, rem);
    output_kernel<<<1, 256, 0, stream>>>(boxes, rem, (float4*)d_out);
}